// Round 12
// baseline (75.633 us; speedup 1.0000x reference)
//
#include <hip/hip_runtime.h>

typedef __attribute__((ext_vector_type(8))) short bf16x8;
typedef __attribute__((ext_vector_type(4))) float f32x4;
typedef unsigned short u16;

#define D_MODEL 1024
#define ROWS 32            // rows per block (down/fused): grid 512, 2 blocks/CU

// Packed-weight geometry: fragments of 512 bf16 (64 lanes x 8), frag(nt,kt).
// Phase-1 B: 17 col-tiles (16 down + 1 gate-padded) x 32 k-tiles (K=1024).
// Phase-2 B: 64 col-tiles (N=1024)                x  8 k-tiles (K=256).
#define WD_FRAGS (17 * 32)
#define WU_FRAGS (64 * 8)
#define WD_ELEMS (WD_FRAGS * 512)   // 278528 bf16
#define WU_ELEMS (WU_FRAGS * 512)   // 262144 bf16

#define LDS_FUSED 49664
#define TB_STRIDE 260

__device__ __forceinline__ u16 f2bf(float f) {  // RNE f32 -> bf16
  union { float f; unsigned u; } v; v.f = f;
  return (u16)((v.u + 0x7fffu + ((v.u >> 16) & 1u)) >> 16);
}

__global__ void lora_prep(const float* __restrict__ Wd, const float* __restrict__ Wu,
                          const float* __restrict__ Wg,
                          u16* __restrict__ wd_pack, u16* __restrict__ wu_pack) {
  int idx = blockIdx.x * 256 + threadIdx.x;
  if (idx < WD_ELEMS) {
    int frag = idx >> 9, w = idx & 511;
    int lane = w >> 3, j = w & 7;
    int nt = frag >> 5, kt = frag & 31;
    int k = kt * 32 + (lane >> 4) * 8 + j;        // 0..1023
    int col = nt * 16 + (lane & 15);              // 0..271
    float v;
    if (col < 256) {
      v = Wd[((col >> 6) * 1024 + k) * 64 + (col & 63)];   // W_down[e][k][a]
    } else {
      int c2 = col - 256;
      v = (c2 < 4) ? Wg[k * 4 + c2] : 0.f;                 // W_gate[k][e], zero-padded
    }
    wd_pack[idx] = f2bf(v);
  } else if (idx < WD_ELEMS + WU_ELEMS) {
    int u = idx - WD_ELEMS;
    int frag = u >> 9, w = u & 511;
    int lane = w >> 3, j = w & 7;
    int nt = frag >> 3, kt = frag & 7;
    int k = kt * 32 + (lane >> 4) * 8 + j;        // 0..255 (= e*64 + a)
    int col = nt * 16 + (lane & 15);              // 0..1023
    wu_pack[u] = f2bf(Wu[((k >> 6) * 64 + (k & 63)) * 1024 + col]);  // W_up[e][a][d]
  }
}

// LDS chunk tile: [32 rows][256 k] bf16, row stride 512 B, XOR-swizzled.
__device__ __forceinline__ void pack_store(char* dst, int r, int col, float4 v0, float4 v1) {
  bf16x8 h;
  h[0] = (short)f2bf(v0.x); h[1] = (short)f2bf(v0.y);
  h[2] = (short)f2bf(v0.z); h[3] = (short)f2bf(v0.w);
  h[4] = (short)f2bf(v1.x); h[5] = (short)f2bf(v1.y);
  h[6] = (short)f2bf(v1.z); h[7] = (short)f2bf(v1.w);
  int cb = col * 2;
  *(bf16x8*)(dst + r * 512 + (cb ^ ((r & 7) << 4))) = h;
}

// ============ split kernel A: x @ Wd -> gated, packed A-fragments in ws ============
__global__ __launch_bounds__(512, 4) void lora_down(
    const float* __restrict__ x, const float* __restrict__ b_gate,
    const u16* __restrict__ wd_pack, u16* __restrict__ afrag) {
  extern __shared__ char smem[];
  const int tid = threadIdx.x, lane = tid & 63, wave = tid >> 6;
  const int l15 = lane & 15, lg = lane >> 4;
  const size_t row0 = (size_t)blockIdx.x * ROWS;
  const float* xblk = x + row0 * D_MODEL;

  f32x4 acc[2][2];
  f32x4 accg[2];
#pragma unroll
  for (int i = 0; i < 2; ++i)
#pragma unroll
    for (int r = 0; r < 2; ++r) acc[i][r] = {0.f, 0.f, 0.f, 0.f};
#pragma unroll
  for (int r = 0; r < 2; ++r) accg[r] = {0.f, 0.f, 0.f, 0.f};

#pragma unroll
  for (int it = 0; it < 2; ++it) {
    int flat = it * 4096 + tid * 8;
    int r = flat >> 8, col = flat & 255;
    float4 v0 = *(const float4*)(xblk + r * D_MODEL + col);
    float4 v1 = *(const float4*)(xblk + r * D_MODEL + col + 4);
    pack_store(smem, r, col, v0, v1);
  }
  __syncthreads();

  float4 pre[4];
  bf16x8 bq[3][2];
  bf16x8 gq[3];
#pragma unroll 1
  for (int c = 0; c < 4; ++c) {
    if (c < 3) {
      const float* src = xblk + (c + 1) * 256;
#pragma unroll
      for (int it = 0; it < 2; ++it) {
        int flat = it * 4096 + tid * 8;
        int r = flat >> 8, col = flat & 255;
        pre[2 * it]     = *(const float4*)(src + r * D_MODEL + col);
        pre[2 * it + 1] = *(const float4*)(src + r * D_MODEL + col + 4);
      }
    }
    const char* buf = smem + (c & 1) * 16384;
#pragma unroll
    for (int pk = 0; pk < 2; ++pk) {
      int ktg = c * 8 + pk;
#pragma unroll
      for (int i = 0; i < 2; ++i)
        bq[pk][i] = *(const bf16x8*)(wd_pack + (size_t)((wave + i * 8) * 32 + ktg) * 512 + lane * 8);
      gq[pk] = *(const bf16x8*)(wd_pack + (size_t)(512 + ktg) * 512 + lane * 8);
    }
#pragma unroll
    for (int ks = 0; ks < 8; ++ks) {
      const int s = ks % 3;
      if (ks < 6) {
        int ktg2 = c * 8 + ks + 2;
        int s2 = (ks + 2) % 3;
#pragma unroll
        for (int i = 0; i < 2; ++i)
          bq[s2][i] = *(const bf16x8*)(wd_pack + (size_t)((wave + i * 8) * 32 + ktg2) * 512 + lane * 8);
        gq[s2] = *(const bf16x8*)(wd_pack + (size_t)(512 + ktg2) * 512 + lane * 8);
      }
      bf16x8 a[2];
#pragma unroll
      for (int r = 0; r < 2; ++r) {
        int rr = r * 16 + l15;
        int cb = (ks * 32 + lg * 8) * 2;
        a[r] = *(const bf16x8*)(buf + rr * 512 + (cb ^ ((rr & 7) << 4)));
      }
#pragma unroll
      for (int i = 0; i < 2; ++i)
#pragma unroll
        for (int r = 0; r < 2; ++r)
          acc[i][r] = __builtin_amdgcn_mfma_f32_16x16x32_bf16(a[r], bq[s][i], acc[i][r], 0, 0, 0);
#pragma unroll
      for (int r = 0; r < 2; ++r)
        accg[r] = __builtin_amdgcn_mfma_f32_16x16x32_bf16(a[r], gq[s], accg[r], 0, 0, 0);
    }
    if (c < 3) {
      char* dst = smem + ((c + 1) & 1) * 16384;
#pragma unroll
      for (int it = 0; it < 2; ++it) {
        int flat = it * 4096 + tid * 8;
        int r = flat >> 8, col = flat & 255;
        pack_store(dst, r, col, pre[2 * it], pre[2 * it + 1]);
      }
      __syncthreads();
    }
  }

  // in-register gate softmax (R11-proven): expert = l15 (0..3 valid), butterfly bits 0-1.
  float gown[2][4];
  {
    const float bg = b_gate[l15 & 3];
#pragma unroll
    for (int r = 0; r < 2; ++r)
#pragma unroll
      for (int j = 0; j < 4; ++j) {
        float v = accg[r][j] + bg;
        float m1 = fmaxf(v, __shfl_xor(v, 1));
        float mx = fmaxf(m1, __shfl_xor(m1, 2));
        float ex = expf(v - mx);
        float s1 = ex + __shfl_xor(ex, 1);
        float sm = s1 + __shfl_xor(s1, 2);
        gown[r][j] = ex / sm;
      }
  }

  // apply gate, pack to buf0 (swizzled, k=e*64+a)
  char* ds = smem;
#pragma unroll
  for (int i = 0; i < 2; ++i) {
    int nt = wave + i * 8;
    int col = nt * 16 + l15;
    int e = nt >> 2;
    int src = lg * 16 + e;
    int cb = col * 2;
#pragma unroll
    for (int r = 0; r < 2; ++r) {
#pragma unroll
      for (int j = 0; j < 4; ++j) {
        float gv = __shfl(gown[r][j], src);
        int row = r * 16 + lg * 4 + j;
        float val = acc[i][r][j] * gv;
        *(u16*)(ds + row * 512 + (cb ^ ((row & 7) << 4))) = f2bf(val);
      }
    }
  }
  __syncthreads();

  // dump A-fragments to ws: frag index ((rt*8 + ks)*2 + r), rt = blockIdx.x.
  // wave w handles ks = w; coalesced 1 KB stores.
  {
    const int ks = wave;
#pragma unroll
    for (int r = 0; r < 2; ++r) {
      int rr = r * 16 + l15;
      int cb = (ks * 32 + lg * 8) * 2;
      bf16x8 a = *(const bf16x8*)(ds + rr * 512 + (cb ^ ((rr & 7) << 4)));
      *(bf16x8*)(afrag + (((size_t)blockIdx.x * 8 + ks) * 2 + r) * 512 + lane * 8) = a;
    }
  }
}

// ============ split kernel B: afrag @ Wup -> out (B in registers) ============
// grid = (N/128) x (M/256) flattened: bx = blockIdx.x & 7, by = blockIdx.x >> 3.
// Block: 8 waves; wave w owns col-tile nt = bx*8 + w; loops 8 row-tiles of 32.
#define TBW 132
__global__ __launch_bounds__(512, 4) void lora_up(
    const u16* __restrict__ afrag, const u16* __restrict__ wu_pack,
    float* __restrict__ out) {
  extern __shared__ char smem[];
  float* tb = (float*)smem;             // 2 x [32][TBW] f32 ping-pong
  const int tid = threadIdx.x, lane = tid & 63, wave = tid >> 6;
  const int l15 = lane & 15, lg = lane >> 4;
  const int bx = blockIdx.x & 7;
  const int by = blockIdx.x >> 3;
  const int nt = bx * 8 + wave;

  bf16x8 bw[8];                         // whole Wup col-tile in registers
#pragma unroll
  for (int kt = 0; kt < 8; ++kt)
    bw[kt] = *(const bf16x8*)(wu_pack + (size_t)(nt * 8 + kt) * 512 + lane * 8);

#pragma unroll 1
  for (int rti = 0; rti < 8; ++rti) {
    const size_t rt = (size_t)by * 8 + rti;
    const u16* ab = afrag + rt * 8192;  // 8 ks x 2 r x 512 elems
    f32x4 acc[2];
    acc[0] = {0.f, 0.f, 0.f, 0.f}; acc[1] = {0.f, 0.f, 0.f, 0.f};
#pragma unroll
    for (int ks = 0; ks < 8; ++ks) {
      bf16x8 a0 = *(const bf16x8*)(ab + (size_t)(ks * 2 + 0) * 512 + lane * 8);
      bf16x8 a1 = *(const bf16x8*)(ab + (size_t)(ks * 2 + 1) * 512 + lane * 8);
      acc[0] = __builtin_amdgcn_mfma_f32_16x16x32_bf16(a0, bw[ks], acc[0], 0, 0, 0);
      acc[1] = __builtin_amdgcn_mfma_f32_16x16x32_bf16(a1, bw[ks], acc[1], 0, 0, 0);
    }
    float* t = tb + (rti & 1) * (32 * TBW);
    int cl = wave * 16 + l15;
#pragma unroll
    for (int r = 0; r < 2; ++r)
#pragma unroll
      for (int j = 0; j < 4; ++j)
        t[(r * 16 + lg * 4 + j) * TBW + cl] = acc[r][j];
    __syncthreads();
    const size_t row0g = (size_t)by * 256 + rti * 32;
#pragma unroll
    for (int it = 0; it < 2; ++it) {
      int f4 = it * 512 + tid;          // float4 index over 32x128
      int row = f4 >> 5, c4 = (f4 & 31) * 4;
      float4 v = *(const float4*)(t + row * TBW + c4);
      *(float4*)(out + (row0g + row) * D_MODEL + bx * 128 + c4) = v;
    }
  }
}

// ============ fused fallback (R11, proven pass) — used only if ws too small ============
__global__ __launch_bounds__(512, 4) void lora_fused(
    const float* __restrict__ x, const float* __restrict__ b_gate,
    const u16* __restrict__ wd_pack, const u16* __restrict__ wu_pack,
    float* __restrict__ out) {
  extern __shared__ char smem[];
  const int tid = threadIdx.x, lane = tid & 63, wave = tid >> 6;
  const int l15 = lane & 15, lg = lane >> 4;
  const size_t row0 = (size_t)blockIdx.x * ROWS;
  const float* xblk = x + row0 * D_MODEL;
  f32x4 acc[2][2]; f32x4 accg[2];
#pragma unroll
  for (int i = 0; i < 2; ++i)
#pragma unroll
    for (int r = 0; r < 2; ++r) acc[i][r] = {0.f, 0.f, 0.f, 0.f};
#pragma unroll
  for (int r = 0; r < 2; ++r) accg[r] = {0.f, 0.f, 0.f, 0.f};
#pragma unroll
  for (int it = 0; it < 2; ++it) {
    int flat = it * 4096 + tid * 8;
    int r = flat >> 8, col = flat & 255;
    float4 v0 = *(const float4*)(xblk + r * D_MODEL + col);
    float4 v1 = *(const float4*)(xblk + r * D_MODEL + col + 4);
    pack_store(smem, r, col, v0, v1);
  }
  __syncthreads();
  float4 pre[4]; bf16x8 bq[3][2]; bf16x8 gq[3];
#pragma unroll 1
  for (int c = 0; c < 4; ++c) {
    if (c < 3) {
      const float* src = xblk + (c + 1) * 256;
#pragma unroll
      for (int it = 0; it < 2; ++it) {
        int flat = it * 4096 + tid * 8;
        int r = flat >> 8, col = flat & 255;
        pre[2 * it]     = *(const float4*)(src + r * D_MODEL + col);
        pre[2 * it + 1] = *(const float4*)(src + r * D_MODEL + col + 4);
      }
    }
    const char* buf = smem + (c & 1) * 16384;
#pragma unroll
    for (int pk = 0; pk < 2; ++pk) {
      int ktg = c * 8 + pk;
#pragma unroll
      for (int i = 0; i < 2; ++i)
        bq[pk][i] = *(const bf16x8*)(wd_pack + (size_t)((wave + i * 8) * 32 + ktg) * 512 + lane * 8);
      gq[pk] = *(const bf16x8*)(wd_pack + (size_t)(512 + ktg) * 512 + lane * 8);
    }
#pragma unroll
    for (int ks = 0; ks < 8; ++ks) {
      const int s = ks % 3;
      if (ks < 6) {
        int ktg2 = c * 8 + ks + 2;
        int s2 = (ks + 2) % 3;
#pragma unroll
        for (int i = 0; i < 2; ++i)
          bq[s2][i] = *(const bf16x8*)(wd_pack + (size_t)((wave + i * 8) * 32 + ktg2) * 512 + lane * 8);
        gq[s2] = *(const bf16x8*)(wd_pack + (size_t)(512 + ktg2) * 512 + lane * 8);
      }
      bf16x8 a[2];
#pragma unroll
      for (int r = 0; r < 2; ++r) {
        int rr = r * 16 + l15;
        int cb = (ks * 32 + lg * 8) * 2;
        a[r] = *(const bf16x8*)(buf + rr * 512 + (cb ^ ((rr & 7) << 4)));
      }
#pragma unroll
      for (int i = 0; i < 2; ++i)
#pragma unroll
        for (int r = 0; r < 2; ++r)
          acc[i][r] = __builtin_amdgcn_mfma_f32_16x16x32_bf16(a[r], bq[s][i], acc[i][r], 0, 0, 0);
#pragma unroll
      for (int r = 0; r < 2; ++r)
        accg[r] = __builtin_amdgcn_mfma_f32_16x16x32_bf16(a[r], gq[s], accg[r], 0, 0, 0);
    }
    if (c < 3) {
      char* dst = smem + ((c + 1) & 1) * 16384;
#pragma unroll
      for (int it = 0; it < 2; ++it) {
        int flat = it * 4096 + tid * 8;
        int r = flat >> 8, col = flat & 255;
        pack_store(dst, r, col, pre[2 * it], pre[2 * it + 1]);
      }
      __syncthreads();
    }
  }
  float gown[2][4];
  {
    const float bg = b_gate[l15 & 3];
#pragma unroll
    for (int r = 0; r < 2; ++r)
#pragma unroll
      for (int j = 0; j < 4; ++j) {
        float v = accg[r][j] + bg;
        float m1 = fmaxf(v, __shfl_xor(v, 1));
        float mx = fmaxf(m1, __shfl_xor(m1, 2));
        float ex = expf(v - mx);
        float s1 = ex + __shfl_xor(ex, 1);
        float sm = s1 + __shfl_xor(s1, 2);
        gown[r][j] = ex / sm;
      }
  }
  char* ds = smem;
#pragma unroll
  for (int i = 0; i < 2; ++i) {
    int nt = wave + i * 8;
    int col = nt * 16 + l15;
    int e = nt >> 2;
    int src = lg * 16 + e;
    int cb = col * 2;
#pragma unroll
    for (int r = 0; r < 2; ++r) {
#pragma unroll
      for (int j = 0; j < 4; ++j) {
        float gv = __shfl(gown[r][j], src);
        int row = r * 16 + lg * 4 + j;
        *(u16*)(ds + row * 512 + (cb ^ ((row & 7) << 4))) = f2bf(acc[i][r][j] * gv);
      }
    }
  }
  __syncthreads();
  float* tb = (float*)(smem + 16384);
  bf16x8 b2[3][2];
#pragma unroll 1
  for (int nc = 0; nc < 4; ++nc) {
    f32x4 acc2[2][2];
#pragma unroll
    for (int i = 0; i < 2; ++i)
#pragma unroll
      for (int r = 0; r < 2; ++r) acc2[i][r] = {0.f, 0.f, 0.f, 0.f};
#pragma unroll
    for (int pk = 0; pk < 2; ++pk)
#pragma unroll
      for (int i = 0; i < 2; ++i)
        b2[pk][i] = *(const bf16x8*)(wu_pack + (size_t)((nc * 16 + wave * 2 + i) * 8 + pk) * 512 + lane * 8);
#pragma unroll
    for (int ks = 0; ks < 8; ++ks) {
      const int s = ks % 3;
      if (ks < 6) {
        int s2 = (ks + 2) % 3;
#pragma unroll
        for (int i = 0; i < 2; ++i)
          b2[s2][i] = *(const bf16x8*)(wu_pack + (size_t)((nc * 16 + wave * 2 + i) * 8 + ks + 2) * 512 + lane * 8);
      }
      bf16x8 a[2];
#pragma unroll
      for (int r = 0; r < 2; ++r) {
        int rr = r * 16 + l15;
        int cb = (ks * 32 + lg * 8) * 2;
        a[r] = *(const bf16x8*)(ds + rr * 512 + (cb ^ ((rr & 7) << 4)));
      }
#pragma unroll
      for (int i = 0; i < 2; ++i)
#pragma unroll
        for (int r = 0; r < 2; ++r)
          acc2[i][r] = __builtin_amdgcn_mfma_f32_16x16x32_bf16(a[r], b2[s][i], acc2[i][r], 0, 0, 0);
    }
#pragma unroll
    for (int i = 0; i < 2; ++i) {
      int cl = wave * 32 + i * 16 + l15;
#pragma unroll
      for (int r = 0; r < 2; ++r)
#pragma unroll
        for (int j = 0; j < 4; ++j)
          tb[(r * 16 + lg * 4 + j) * TB_STRIDE + cl] = acc2[i][r][j];
    }
    __syncthreads();
#pragma unroll
    for (int it = 0; it < 4; ++it) {
      int flat = it * 2048 + tid * 4;
      int row = flat >> 8, col = flat & 255;
      float4 v = *(const float4*)(tb + row * TB_STRIDE + col);
      *(float4*)(out + (row0 + row) * D_MODEL + nc * 256 + col) = v;
    }
    __syncthreads();
  }
}

extern "C" void kernel_launch(void* const* d_in, const int* in_sizes, int n_in,
                              void* d_out, int out_size, void* d_ws, size_t ws_size,
                              hipStream_t stream) {
  const float* x  = (const float*)d_in[0];
  const float* Wd = (const float*)d_in[1];
  const float* Wu = (const float*)d_in[2];
  const float* Wg = (const float*)d_in[3];
  const float* bg = (const float*)d_in[4];
  float* out = (float*)d_out;
  const int M = in_sizes[0] / D_MODEL;  // 16384

  u16* wd_pack = (u16*)d_ws;            // 557056 B
  u16* wu_pack = wd_pack + WD_ELEMS;    // +524288 B
  u16* afrag   = wu_pack + WU_ELEMS;    // +M*256*2 B (8 MB at M=16384)

  const size_t need = (size_t)(WD_ELEMS + WU_ELEMS) * 2 + (size_t)M * 256 * 2;
  const int total = WD_ELEMS + WU_ELEMS;
  lora_prep<<<(total + 255) / 256, 256, 0, stream>>>(Wd, Wu, Wg, wd_pack, wu_pack);

  if (ws_size >= need && (M % 256) == 0) {
    lora_down<<<M / ROWS, 512, 32768, stream>>>(x, bg, wd_pack, afrag);
    lora_up<<<8 * (M / 256), 512, 2 * 32 * TBW * 4, stream>>>(afrag, wu_pack, out);
  } else {
    lora_fused<<<M / ROWS, 512, LDS_FUSED, stream>>>(x, bg, wd_pack, wu_pack, out);
  }
}